// Round 7
// baseline (276.264 us; speedup 1.0000x reference)
//
#include <hip/hip_runtime.h>
#include <math.h>

// Problem constants (B=8, Cin=Cout=64, H=W=64, 3x3 kernel pad 1)
#define NB     8
#define NC     64
#define HW     4096           // 64*64
#define PLANE  2097152        // NB*NC*HW

// Workspace layout (float-slot offsets)
#define WS_WB     0           // bf16 wB[8][72][64][8]   (294912 bf16 = 147456 f)
#define WS_OWB    147456      // bf16 owB[8][72][32][8]  (147456 bf16 = 73728 f)
#define WS_OB     221184      // f32 obAll[8][27]
#define WS_GATES  221400      // f32 gates_scr[4][8][64][4096] = 8388608 (D-scrambled)
#define WS_XT     8610008     // bf16 xT[8][4096][64] HWC  (1048576 f)
#define WS_HT     9658584     // bf16 hT[8][4096][64] HWC  (1048576 f)
// total = 10707160 floats = 42.8 MB

typedef __bf16 bf16x8 __attribute__((ext_vector_type(8)));
typedef float  f32x4  __attribute__((ext_vector_type(4)));
typedef _Float16 f16x4 __attribute__((ext_vector_type(4)));

struct Params {
    const float* x; const float* h; const float* c;
    const float* w[8]; const float* ow[8]; const float* ob[8];
    const float* bi; const float* bf; const float* bc; const float* bo;
    const float* wci; const float* wcf; const float* wco;
    float* out; float* ws;
};

__device__ __forceinline__ float sigf(float v) { return 1.f / (1.f + __expf(-v)); }
__device__ __forceinline__ float tanhfast(float v) {
    return 1.f - 2.f / (__expf(2.f * v) + 1.f);
}
__device__ __forceinline__ unsigned short f2bf(float v) {
    __bf16 b = (__bf16)v;
    return __builtin_bit_cast(unsigned short, b);
}
// bf16 pair unpack: lo/hi halves of a dword -> f32 (1 inst each)
__device__ __forceinline__ float blo(unsigned d) { return __builtin_bit_cast(float, d << 16); }
__device__ __forceinline__ float bhi(unsigned d) { return __builtin_bit_cast(float, d & 0xffff0000u); }

// ---------------------------------------------------------------------------
// K0 (merged): weight B-frag packing + biases (blocks 0..1728), and
//   CHW fp32 -> HWC bf16 transpose of x/h (blocks 1729..2752).
// ---------------------------------------------------------------------------
__global__ __launch_bounds__(256) void k0_prep(Params p) {
    if (blockIdx.x < 1729) {
        int i = blockIdx.x * 256 + threadIdx.x;
        unsigned short* wb  = (unsigned short*)(p.ws + WS_WB);
        unsigned short* owb = (unsigned short*)(p.ws + WS_OWB);
        if (i < 294912) {
            int br = i / 36864; int r = i % 36864;
            int kgrp = r >> 9; int o = (r >> 3) & 63; int j = r & 7;
            int k = kgrp * 8 + j;
            int ktap = k >> 6; int c = k & 63;
            wb[i] = f2bf(p.w[br][(o * 64 + c) * 9 + ktap]);
        } else if (i < 294912 + 147456) {
            int ii = i - 294912;
            int br = ii / 18432; int r = ii % 18432;
            int kgrp = r >> 8; int o = (r >> 3) & 31; int j = r & 7;
            int k = kgrp * 8 + j;
            int ktap = k >> 6; int c = k & 63;
            float v = (o < 27) ? p.ow[br][(o * 64 + c) * 9 + ktap] : 0.f;
            owb[ii] = f2bf(v);
        } else if (i < 294912 + 147456 + 216) {
            int ii = i - 442368;
            int br = ii / 27; int j = ii % 27;
            p.ws[WS_OB + ii] = p.ob[br][j];
        }
        return;
    }
    __shared__ float tile[64][65];
    int bid = blockIdx.x - 1729;
    int row = bid & 63; int b = (bid >> 6) & 7; int ten = bid >> 9;
    const float* src = ten ? p.h : p.x;
    unsigned short* dst = (unsigned short*)(p.ws + (ten ? WS_HT : WS_XT));
    int t = threadIdx.x; int lane = t & 63; int w4 = t >> 6;
#pragma unroll
    for (int i = 0; i < 16; ++i) {
        int c = i * 4 + w4;
        tile[c][lane] = src[((size_t)(b * 64 + c) << 12) + row * 64 + lane];
    }
    __syncthreads();
#pragma unroll
    for (int i = 0; i < 16; ++i) {
        int px = i * 4 + w4;
        dst[((size_t)(b * 4096 + row * 64 + px) << 6) + lane] = f2bf(tile[lane][px]);
    }
}

// ---------------------------------------------------------------------------
// K2 v15 (arena <=40KB -> 4 blocks/CU): offset-conv + deform + MFMA.
//   R6 post-mortem: 3 blocks/CU landed (occ 28.9, VALU 61%) but the gains
//   were offset by the extra half-pass work; VGPR collapsed to 76 (lots of
//   headroom). Bank-conflict growth tracks LDS inst count, not per-access
//   regression (stage writes / gather reads verified even over bank-quads).
//   THIS ROUND (no structural change, pure residency):
//     - sWp stored as f16x4 (8B) instead of float4 (16B): -4608B. Weights
//       in [0,1]; f16 relerr ~5e-4 << bf16 path's 4e-3.
//     - sOff only rows j<27 are read -> [27][66] f32, guard j>=27 writes:
//       -1320B.
//     - arena 42752 -> 36864B => 4 blocks/CU (147/160KB), 4 waves/SIMD.
//     - __launch_bounds__(256,4): VGPR budget 128 vs measured 76 -> safe.
//   Carried: half-channel window passes (R6), LDS window gather (R4), XOR
//   bank swizzle, far-bit global fallback, B-frag register pipeline (R5),
//   XCD swizzle b=bid&7, D-scrambled epilogue.
// ---------------------------------------------------------------------------
__global__ __launch_bounds__(256, 4) void k2_fused(Params p) {
    __shared__ __align__(16) unsigned char arena[36864];
    // win:   [0, 20480)      bf16 [5][64px][32ch], byte=((r*64+px)<<6)+seg*16 ^ ((px&7)<<4)
    // sA:    [20480, 25088)  uint2 [9][64]  packed clamped pix (+far bit31 in .x)
    // sWp:   [25088, 29696)  f16x4 [9][64]  folded bilinear weights
    // sOff:  [29696, 36824)  f32 [27][66]
    uint2* sA   = (uint2*)(arena + 20480);
    f16x4* sWp  = (f16x4*)(arena + 25088);
    float* sOff = (float*)(arena + 29696);

    int bid = blockIdx.x;
    // XCD-aware decode: same-b blocks share an XCD's L2.
    int b = bid & 7; int gate = (bid >> 3) & 3; int row = bid >> 5;
    int t = threadIdx.x; int l = t & 63; int w = t >> 6;
    int q = l >> 4; int n = l & 15;
    int pxl = w * 16 + n;

    const unsigned short* wBp = (const unsigned short*)(p.ws + WS_WB);
    const unsigned short* owb = (const unsigned short*)(p.ws + WS_OWB);

    // per-lane gather address bias: byte = (pix<<6) + qb, then ^ ((pix&7)<<4)
    int qb = q * 16 - (row - 2) * 4096;

    f32x4 acc[4];
#pragma unroll
    for (int ot = 0; ot < 4; ++ot) acc[ot] = (f32x4){0.f, 0.f, 0.f, 0.f};

    for (int sub = 0; sub < 2; ++sub) {
        int br = gate * 2 + sub;
        const unsigned short* inT =
            (const unsigned short*)(p.ws + (sub ? WS_HT : WS_XT)) + ((size_t)b << 18);
        const float* obp = p.ws + WS_OB + br * 27;

        // ---- stage one 32-ch half of the 5-row window (zero-filled OOB) ----
        auto stage_half = [&](int half) {
#pragma unroll
            for (int it = 0; it < 5; ++it) {
                int u = t + it * 256;                  // u in [0,1280)
                int r = u >> 8; int px = (u >> 2) & 63; int seg = u & 3;
                int grow = row - 2 + r;
                uint4 v = {0u, 0u, 0u, 0u};
                if ((unsigned)grow < 64u)
                    v = *(const uint4*)(inT + (((size_t)grow * 64 + px) << 6) + half * 32 + seg * 8);
                unsigned byte = ((unsigned)u << 4) ^ (((unsigned)px & 7u) << 4);
                *(uint4*)(arena + byte) = v;
            }
        };

        // ---- offset-conv helpers: slice sl in [0,9): dy=sl/3, dxk=sl%3 ----
        auto loadA_oc = [&](int sl) -> bf16x8 {
            int dy = sl / 3; int dxk = sl % 3;
            int spx = pxl + dxk - 1;                  // [-1, 64]
            int spc = min(max(spx, 0), 63);
            unsigned byte = ((unsigned)((((dy + 1) * 64 + spc) << 6) + q * 16))
                            ^ (((unsigned)spc & 7u) << 4);
            bf16x8 af = *(const bf16x8*)(arena + byte);
            if ((unsigned)spx >= 64u) {               // zero halo columns
#pragma unroll
                for (int z = 0; z < 8; ++z) af[z] = (__bf16)0.f;
            }
            return af;
        };
        auto loadB_oc = [&](int sl, int half, int ot) -> bf16x8 {
            int dy = sl / 3; int dxk = sl % 3; int s = dxk * 2 + half;
            int kb = (br * 72 + dy * 24 + s * 4 + q) * 32;
            return *(const bf16x8*)(owb + (size_t)(kb + ot * 16 + n) * 8);
        };
        auto offconv_pass = [&](int half, f32x4& cA, f32x4& cB) {
            bf16x8 a0 = loadA_oc(0), b0 = loadB_oc(0, half, 0), b1 = loadB_oc(0, half, 1);
#pragma unroll 1
            for (int sl = 0; sl < 9; ++sl) {
                bf16x8 na = a0, nb0 = b0, nb1 = b1;
                if (sl < 8) {
                    na = loadA_oc(sl + 1); nb0 = loadB_oc(sl + 1, half, 0); nb1 = loadB_oc(sl + 1, half, 1);
                }
                cA = __builtin_amdgcn_mfma_f32_16x16x32_bf16(a0, b0, cA, 0, 0, 0);
                cB = __builtin_amdgcn_mfma_f32_16x16x32_bf16(a0, b1, cB, 0, 0, 0);
                a0 = na; b0 = nb0; b1 = nb1;
            }
        };

        f32x4 c0 = (f32x4){0.f,0.f,0.f,0.f}, c1 = (f32x4){0.f,0.f,0.f,0.f};
        f32x4 c2 = (f32x4){0.f,0.f,0.f,0.f}, c3 = (f32x4){0.f,0.f,0.f,0.f};

        __syncthreads();           // window/sA/sWp free (prev sub done)
        stage_half(0);
        __syncthreads();
        offconv_pass(0, c0, c1);   // s even K-slices (ch 0..31)
        __syncthreads();           // all waves done reading half-0 window
        stage_half(1);
        __syncthreads();
        offconv_pass(1, c2, c3);   // s odd K-slices (ch 32..63)

        f32x4 acc2[2];
        acc2[0] = c0 + c2;
        acc2[1] = c1 + c3;

        // D-frags (+bias) -> sOff[j][px]; j=ot*16+n, px=w*16+q*4+r; j<27 only
#pragma unroll
        for (int ot = 0; ot < 2; ++ot) {
            int j = ot * 16 + n;
            if (j < 27) {
                float bias = obp[j];
#pragma unroll
                for (int r = 0; r < 4; ++r)
                    sOff[j * 66 + w * 16 + q * 4 + r] = acc2[ot][r] + bias;
            }
        }
        __syncthreads();   // sOff visible

        // ---- Phase A: bilinear coords + (mask*inbound)-folded weights ----
        for (int i2 = t; i2 < 576; i2 += 256) {
            int px = i2 & 63; int k = i2 >> 6;
            float dy = sOff[(2 * k) * 66 + px];
            float dx = sOff[(2 * k + 1) * 66 + px];
            float mm = sOff[(18 + k) * 66 + px];
            float m = sigf(mm);
            int ki = k / 3, kj = k % 3;
            float py  = (float)(row + ki - 1) + dy;
            float pxx = (float)(px + kj - 1) + dx;
            float y0f = floorf(py), x0f = floorf(pxx);
            float wy = py - y0f, wx = pxx - x0f;
            int y0 = (int)y0f, x0 = (int)x0f;
            float y0i = ((unsigned)y0 < 64u) ? 1.f : 0.f;
            float y1i = ((unsigned)(y0 + 1) < 64u) ? 1.f : 0.f;
            float x0i = ((unsigned)x0 < 64u) ? 1.f : 0.f;
            float x1i = ((unsigned)(x0 + 1) < 64u) ? 1.f : 0.f;
            float w00 = (1.f - wy) * (1.f - wx) * m * y0i * x0i;
            float w01 = (1.f - wy) * wx         * m * y0i * x1i;
            float w10 = wy         * (1.f - wx) * m * y1i * x0i;
            float w11 = wy         * wx         * m * y1i * x1i;
            int cy0 = min(max(y0, 0), 63),     cy1 = min(max(y0 + 1, 0), 63);
            int cx0 = min(max(x0, 0), 63),     cx1 = min(max(x0 + 1, 0), 63);
            // far: clamped corner row outside staged window [row-2, row+2]
            int s0 = cy0 - (row - 2); int s1 = cy1 - (row - 2);
            unsigned farb = (((unsigned)s0 > 4u) || ((unsigned)s1 > 4u)) ? 0x80000000u : 0u;
            sA[k * 64 + px] = make_uint2(((unsigned)(cy0 * 64 + cx0) | ((unsigned)(cy0 * 64 + cx1) << 16)) | farb,
                                         (unsigned)(cy1 * 64 + cx0) | ((unsigned)(cy1 * 64 + cx1) << 16));
            sWp[k * 64 + px] = (f16x4){(_Float16)w00, (_Float16)w01, (_Float16)w10, (_Float16)w11};
        }
        __syncthreads();

        // ---- per-half pipelined LDS gather + B-frag register pipeline ----
        auto loadB_mn = [&](int S, int ot) -> bf16x8 {
            int kb = (br * 72 + S * 4 + q) * 64;
            return *(const bf16x8*)(wBp + (size_t)(kb + ot * 16 + n) * 8);
        };

#define PROC(Ca, Cb, Cc, Cd, WV, Wa, Wb, Wc, Wd)                               \
        {                                                                      \
            float sacc[8];                                                     \
            sacc[0] = WV.x * blo(Ca.x); sacc[1] = WV.x * bhi(Ca.x);            \
            sacc[2] = WV.x * blo(Ca.y); sacc[3] = WV.x * bhi(Ca.y);            \
            sacc[4] = WV.x * blo(Ca.z); sacc[5] = WV.x * bhi(Ca.z);            \
            sacc[6] = WV.x * blo(Ca.w); sacc[7] = WV.x * bhi(Ca.w);            \
            sacc[0] += WV.y * blo(Cb.x); sacc[1] += WV.y * bhi(Cb.x);          \
            sacc[2] += WV.y * blo(Cb.y); sacc[3] += WV.y * bhi(Cb.y);          \
            sacc[4] += WV.y * blo(Cb.z); sacc[5] += WV.y * bhi(Cb.z);          \
            sacc[6] += WV.y * blo(Cb.w); sacc[7] += WV.y * bhi(Cb.w);          \
            sacc[0] += WV.z * blo(Cc.x); sacc[1] += WV.z * bhi(Cc.x);          \
            sacc[2] += WV.z * blo(Cc.y); sacc[3] += WV.z * bhi(Cc.y);          \
            sacc[4] += WV.z * blo(Cc.z); sacc[5] += WV.z * bhi(Cc.z);          \
            sacc[6] += WV.z * blo(Cc.w); sacc[7] += WV.z * bhi(Cc.w);          \
            sacc[0] += WV.w * blo(Cd.x); sacc[1] += WV.w * bhi(Cd.x);          \
            sacc[2] += WV.w * blo(Cd.y); sacc[3] += WV.w * bhi(Cd.y);          \
            sacc[4] += WV.w * blo(Cd.z); sacc[5] += WV.w * bhi(Cd.z);          \
            sacc[6] += WV.w * blo(Cd.w); sacc[7] += WV.w * bhi(Cd.w);          \
            bf16x8 af;                                                         \
            _Pragma("unroll")                                                  \
            for (int j = 0; j < 8; ++j) af[j] = (__bf16)sacc[j];               \
            acc[0] = __builtin_amdgcn_mfma_f32_16x16x32_bf16(af, Wa, acc[0], 0, 0, 0); \
            acc[1] = __builtin_amdgcn_mfma_f32_16x16x32_bf16(af, Wb, acc[1], 0, 0, 0); \
            acc[2] = __builtin_amdgcn_mfma_f32_16x16x32_bf16(af, Wc, acc[2], 0, 0, 0); \
            acc[3] = __builtin_amdgcn_mfma_f32_16x16x32_bf16(af, Wd, acc[3], 0, 0, 0); \
        }

        auto gather_pass = [&](int half) {
            const unsigned short* cbaseh = inT + q * 8 + half * 32;
            // prologue: tap 0 addresses, corner LDS loads, tap-0 B-frags
            uint2 aa = sA[pxl];
            f16x4 wv4 = sWp[pxl];
            float4 wv = make_float4((float)wv4[0], (float)wv4[1], (float)wv4[2], (float)wv4[3]);
            unsigned p00 = aa.x & 0xFFFu, p01 = (aa.x >> 16) & 0xFFFu;
            unsigned p10 = aa.y & 0xFFFu, p11 = aa.y >> 16;
            unsigned a00 = (unsigned)(((int)(p00 << 6)) + qb) ^ ((p00 & 7u) << 4);
            unsigned a01 = (unsigned)(((int)(p01 << 6)) + qb) ^ ((p01 & 7u) << 4);
            unsigned a10 = (unsigned)(((int)(p10 << 6)) + qb) ^ ((p10 & 7u) << 4);
            unsigned a11 = (unsigned)(((int)(p11 << 6)) + qb) ^ ((p11 & 7u) << 4);
            uint4 Ca = *(const uint4*)(arena + a00);
            uint4 Cb = *(const uint4*)(arena + a01);
            uint4 Cc = *(const uint4*)(arena + a10);
            uint4 Cd = *(const uint4*)(arena + a11);
            if (aa.x & 0x80000000u) {   // rare: window miss -> exact global path
                Ca = *(const uint4*)(cbaseh + (p00 << 6));
                Cb = *(const uint4*)(cbaseh + (p01 << 6));
                Cc = *(const uint4*)(cbaseh + (p10 << 6));
                Cd = *(const uint4*)(cbaseh + (p11 << 6));
            }
            bf16x8 Ba = loadB_mn(half, 0), Bb = loadB_mn(half, 1);
            bf16x8 Bc = loadB_mn(half, 2), Bd = loadB_mn(half, 3);
#pragma unroll 1
            for (int ktap = 0; ktap < 9; ++ktap) {
                uint4 Na = Ca, Nb = Cb, Nc = Cc, Nd = Cd;
                float4 wvn = wv;
                bf16x8 nBa = Ba, nBb = Bb, nBc = Bc, nBd = Bd;
                if (ktap < 8) {   // prefetch next tap: A corners (LDS) + B (global)
                    uint2 aan = sA[(ktap + 1) * 64 + pxl];
                    f16x4 wvn4 = sWp[(ktap + 1) * 64 + pxl];
                    wvn = make_float4((float)wvn4[0], (float)wvn4[1], (float)wvn4[2], (float)wvn4[3]);
                    unsigned q00 = aan.x & 0xFFFu, q01 = (aan.x >> 16) & 0xFFFu;
                    unsigned q10 = aan.y & 0xFFFu, q11 = aan.y >> 16;
                    unsigned b00 = (unsigned)(((int)(q00 << 6)) + qb) ^ ((q00 & 7u) << 4);
                    unsigned b01 = (unsigned)(((int)(q01 << 6)) + qb) ^ ((q01 & 7u) << 4);
                    unsigned b10 = (unsigned)(((int)(q10 << 6)) + qb) ^ ((q10 & 7u) << 4);
                    unsigned b11 = (unsigned)(((int)(q11 << 6)) + qb) ^ ((q11 & 7u) << 4);
                    Na = *(const uint4*)(arena + b00);
                    Nb = *(const uint4*)(arena + b01);
                    Nc = *(const uint4*)(arena + b10);
                    Nd = *(const uint4*)(arena + b11);
                    if (aan.x & 0x80000000u) {
                        Na = *(const uint4*)(cbaseh + (q00 << 6));
                        Nb = *(const uint4*)(cbaseh + (q01 << 6));
                        Nc = *(const uint4*)(cbaseh + (q10 << 6));
                        Nd = *(const uint4*)(cbaseh + (q11 << 6));
                    }
                    nBa = loadB_mn((ktap + 1) * 2 + half, 0);
                    nBb = loadB_mn((ktap + 1) * 2 + half, 1);
                    nBc = loadB_mn((ktap + 1) * 2 + half, 2);
                    nBd = loadB_mn((ktap + 1) * 2 + half, 3);
                }
                PROC(Ca, Cb, Cc, Cd, wv, Ba, Bb, Bc, Bd)
                Ca = Na; Cb = Nb; Cc = Nc; Cd = Nd;
                Ba = nBa; Bb = nBb; Bc = nBc; Bd = nBd;
                wv = wvn;
            }
        };

        gather_pass(1);            // window currently holds half-1
        __syncthreads();           // all waves done reading half-1 window
        stage_half(0);
        __syncthreads();
        gather_pass(0);
#undef PROC
    }

    // epilogue: direct D-scrambled coalesced store; K3 decodes.
    float* gp = p.ws + WS_GATES + ((size_t)((gate * 8 + b) * 64 + row) << 12);
#pragma unroll
    for (int ot = 0; ot < 4; ++ot)
        *(float4*)(gp + ((w * 4 + ot) * 64 + l) * 4) = *(float4*)&acc[ot];
}

// ---------------------------------------------------------------------------
// K3: pointwise ConvLSTM combine, reading D-scrambled gates (coalesced) and
//   decoding (o,px) for c/out access (16B-segment granularity).
//   grid: 8192 blocks of 256.
// ---------------------------------------------------------------------------
__global__ __launch_bounds__(256) void k3_lstm(Params p) {
    int T = blockIdx.x * 256 + threadIdx.x;        // [b][row][i] over scrambled
    int i = T & 4095; int row = (T >> 12) & 63; int b = T >> 18;
    const float* gp = p.ws + WS_GATES;
    size_t base = ((size_t)(b * 64 + row) << 12) + i;
    float gi = gp[base];
    float gf = gp[base + 1 * PLANE];
    float gc = gp[base + 2 * PLANE];
    float go = gp[base + 3 * PLANE];
    // decode scramble: i = ((w*4+ot)*64 + l)*4 + r
    int r = i & 3; int l = (i >> 2) & 63; int u = i >> 8;
    int w = u >> 2; int ot = u & 3;
    int o = ot * 16 + (l & 15);
    int px = w * 16 + (l >> 4) * 4 + r;
    size_t cidx = ((size_t)(b * 64 + o) << 12) + row * 64 + px;
    float cold = p.c[cidx];
    float ig = sigf(gi + cold * p.wci[o] + p.bi[o]);
    float fg = sigf(gf + cold * p.wcf[o] + p.bf[o]);
    float cn = fg * cold + ig * tanhfast(gc + p.bc[o]);
    float og = sigf(go + cn * p.wco[o] + p.bo[o]);
    p.out[cidx] = og * tanhfast(cn);
    p.out[cidx + PLANE] = cn;
}

// ---------------------------------------------------------------------------
extern "C" void kernel_launch(void* const* d_in, const int* in_sizes, int n_in,
                              void* d_out, int out_size, void* d_ws, size_t ws_size,
                              hipStream_t stream) {
    (void)in_sizes; (void)n_in; (void)out_size; (void)ws_size;
    Params P;
    P.x = (const float*)d_in[0];
    P.h = (const float*)d_in[1];
    P.c = (const float*)d_in[2];
    for (int i = 0; i < 8; ++i) {
        P.w[i]  = (const float*)d_in[3 + 3 * i];
        P.ow[i] = (const float*)d_in[4 + 3 * i];
        P.ob[i] = (const float*)d_in[5 + 3 * i];
    }
    P.bi  = (const float*)d_in[27];
    P.bf  = (const float*)d_in[28];
    P.bc  = (const float*)d_in[29];
    P.bo  = (const float*)d_in[30];
    P.wci = (const float*)d_in[31];
    P.wcf = (const float*)d_in[32];
    P.wco = (const float*)d_in[33];
    P.out = (float*)d_out;
    P.ws  = (float*)d_ws;

    k0_prep   <<<dim3(2753), dim3(256), 0, stream>>>(P);
    k2_fused  <<<dim3(2048), dim3(256), 0, stream>>>(P);
    k3_lstm   <<<dim3(8192), dim3(256), 0, stream>>>(P);
}

// Round 8
// 273.115 us; speedup vs baseline: 1.0115x; 1.0115x over previous
//
#include <hip/hip_runtime.h>
#include <math.h>

// Problem constants (B=8, Cin=Cout=64, H=W=64, 3x3 kernel pad 1)
#define NB     8
#define NC     64
#define HW     4096           // 64*64
#define PLANE  2097152        // NB*NC*HW

// Workspace layout (float-slot offsets)
#define WS_WB     0           // bf16 wB[8][72][64][8]   (294912 bf16 = 147456 f)
#define WS_OWB    147456      // bf16 owB[8][72][32][8]  (147456 bf16 = 73728 f)
#define WS_OB     221184      // f32 obAll[8][27]
#define WS_GATES  221400      // f32 gates_scr[4][8][64][4096] = 8388608 (D-scrambled)
#define WS_XT     8610008     // bf16 xT[8][4096][64] HWC  (1048576 f)
#define WS_HT     9658584     // bf16 hT[8][4096][64] HWC  (1048576 f)
// total = 10707160 floats = 42.8 MB

typedef __bf16 bf16x8 __attribute__((ext_vector_type(8)));
typedef float  f32x4  __attribute__((ext_vector_type(4)));
typedef _Float16 f16x4 __attribute__((ext_vector_type(4)));

struct Params {
    const float* x; const float* h; const float* c;
    const float* w[8]; const float* ow[8]; const float* ob[8];
    const float* bi; const float* bf; const float* bc; const float* bo;
    const float* wci; const float* wcf; const float* wco;
    float* out; float* ws;
};

__device__ __forceinline__ float sigf(float v) { return 1.f / (1.f + __expf(-v)); }
__device__ __forceinline__ float tanhfast(float v) {
    return 1.f - 2.f / (__expf(2.f * v) + 1.f);
}
__device__ __forceinline__ unsigned short f2bf(float v) {
    __bf16 b = (__bf16)v;
    return __builtin_bit_cast(unsigned short, b);
}
// bf16 pair unpack: lo/hi halves of a dword -> f32 (1 inst each)
__device__ __forceinline__ float blo(unsigned d) { return __builtin_bit_cast(float, d << 16); }
__device__ __forceinline__ float bhi(unsigned d) { return __builtin_bit_cast(float, d & 0xffff0000u); }

// ---------------------------------------------------------------------------
// K0 (merged): weight B-frag packing + biases (blocks 0..1728), and
//   CHW fp32 -> HWC bf16 transpose of x/h (blocks 1729..2752).
// ---------------------------------------------------------------------------
__global__ __launch_bounds__(256) void k0_prep(Params p) {
    if (blockIdx.x < 1729) {
        int i = blockIdx.x * 256 + threadIdx.x;
        unsigned short* wb  = (unsigned short*)(p.ws + WS_WB);
        unsigned short* owb = (unsigned short*)(p.ws + WS_OWB);
        if (i < 294912) {
            int br = i / 36864; int r = i % 36864;
            int kgrp = r >> 9; int o = (r >> 3) & 63; int j = r & 7;
            int k = kgrp * 8 + j;
            int ktap = k >> 6; int c = k & 63;
            wb[i] = f2bf(p.w[br][(o * 64 + c) * 9 + ktap]);
        } else if (i < 294912 + 147456) {
            int ii = i - 294912;
            int br = ii / 18432; int r = ii % 18432;
            int kgrp = r >> 8; int o = (r >> 3) & 31; int j = r & 7;
            int k = kgrp * 8 + j;
            int ktap = k >> 6; int c = k & 63;
            float v = (o < 27) ? p.ow[br][(o * 64 + c) * 9 + ktap] : 0.f;
            owb[ii] = f2bf(v);
        } else if (i < 294912 + 147456 + 216) {
            int ii = i - 442368;
            int br = ii / 27; int j = ii % 27;
            p.ws[WS_OB + ii] = p.ob[br][j];
        }
        return;
    }
    __shared__ float tile[64][65];
    int bid = blockIdx.x - 1729;
    int row = bid & 63; int b = (bid >> 6) & 7; int ten = bid >> 9;
    const float* src = ten ? p.h : p.x;
    unsigned short* dst = (unsigned short*)(p.ws + (ten ? WS_HT : WS_XT));
    int t = threadIdx.x; int lane = t & 63; int w4 = t >> 6;
#pragma unroll
    for (int i = 0; i < 16; ++i) {
        int c = i * 4 + w4;
        tile[c][lane] = src[((size_t)(b * 64 + c) << 12) + row * 64 + lane];
    }
    __syncthreads();
#pragma unroll
    for (int i = 0; i < 16; ++i) {
        int px = i * 4 + w4;
        dst[((size_t)(b * 4096 + row * 64 + px) << 6) + lane] = f2bf(tile[lane][px]);
    }
}

// ---------------------------------------------------------------------------
// K2 v16 (36KB arena + relaxed reg bound): offset-conv + deform + MFMA.
//   R7 post-mortem: __launch_bounds__(256,4) made the allocator target 64
//   arch-VGPRs (same as R1) -> scratch spills (WRITE 33->61MB, FETCH
//   7.6->21MB) that ate the 4-block TLP gain. R6 precedent: this code shape
//   compiles to ~76 regs under (256,3) — already <=128, which by the HW
//   VGPR granularity (waves halve at 64/128/256) qualifies for 4 waves/SIMD
//   on its own. So: KEEP the 36864B arena (4 blocks fit in LDS), REVERT the
//   bound to (256,3) (budget 170, no forced crush). Expected: natural alloc
//   <=128 -> 4 blocks/CU resident with NO spills. Worst case alloc >128 ->
//   3 blocks = R6 baseline (no loss).
//   Carried: half-channel window passes (R6), f16 sWp + 27-row sOff (R7
//   shrink), LDS window gather (R4), XOR bank swizzle, far-bit global
//   fallback, B-frag register pipeline (R5), XCD swizzle b=bid&7,
//   D-scrambled epilogue.
// ---------------------------------------------------------------------------
__global__ __launch_bounds__(256, 3) void k2_fused(Params p) {
    __shared__ __align__(16) unsigned char arena[36864];
    // win:   [0, 20480)      bf16 [5][64px][32ch], byte=((r*64+px)<<6)+seg*16 ^ ((px&7)<<4)
    // sA:    [20480, 25088)  uint2 [9][64]  packed clamped pix (+far bit31 in .x)
    // sWp:   [25088, 29696)  f16x4 [9][64]  folded bilinear weights
    // sOff:  [29696, 36824)  f32 [27][66]
    uint2* sA   = (uint2*)(arena + 20480);
    f16x4* sWp  = (f16x4*)(arena + 25088);
    float* sOff = (float*)(arena + 29696);

    int bid = blockIdx.x;
    // XCD-aware decode: same-b blocks share an XCD's L2.
    int b = bid & 7; int gate = (bid >> 3) & 3; int row = bid >> 5;
    int t = threadIdx.x; int l = t & 63; int w = t >> 6;
    int q = l >> 4; int n = l & 15;
    int pxl = w * 16 + n;

    const unsigned short* wBp = (const unsigned short*)(p.ws + WS_WB);
    const unsigned short* owb = (const unsigned short*)(p.ws + WS_OWB);

    // per-lane gather address bias: byte = (pix<<6) + qb, then ^ ((pix&7)<<4)
    int qb = q * 16 - (row - 2) * 4096;

    f32x4 acc[4];
#pragma unroll
    for (int ot = 0; ot < 4; ++ot) acc[ot] = (f32x4){0.f, 0.f, 0.f, 0.f};

    for (int sub = 0; sub < 2; ++sub) {
        int br = gate * 2 + sub;
        const unsigned short* inT =
            (const unsigned short*)(p.ws + (sub ? WS_HT : WS_XT)) + ((size_t)b << 18);
        const float* obp = p.ws + WS_OB + br * 27;

        // ---- stage one 32-ch half of the 5-row window (zero-filled OOB) ----
        auto stage_half = [&](int half) {
#pragma unroll
            for (int it = 0; it < 5; ++it) {
                int u = t + it * 256;                  // u in [0,1280)
                int r = u >> 8; int px = (u >> 2) & 63; int seg = u & 3;
                int grow = row - 2 + r;
                uint4 v = {0u, 0u, 0u, 0u};
                if ((unsigned)grow < 64u)
                    v = *(const uint4*)(inT + (((size_t)grow * 64 + px) << 6) + half * 32 + seg * 8);
                unsigned byte = ((unsigned)u << 4) ^ (((unsigned)px & 7u) << 4);
                *(uint4*)(arena + byte) = v;
            }
        };

        // ---- offset-conv helpers: slice sl in [0,9): dy=sl/3, dxk=sl%3 ----
        auto loadA_oc = [&](int sl) -> bf16x8 {
            int dy = sl / 3; int dxk = sl % 3;
            int spx = pxl + dxk - 1;                  // [-1, 64]
            int spc = min(max(spx, 0), 63);
            unsigned byte = ((unsigned)((((dy + 1) * 64 + spc) << 6) + q * 16))
                            ^ (((unsigned)spc & 7u) << 4);
            bf16x8 af = *(const bf16x8*)(arena + byte);
            if ((unsigned)spx >= 64u) {               // zero halo columns
#pragma unroll
                for (int z = 0; z < 8; ++z) af[z] = (__bf16)0.f;
            }
            return af;
        };
        auto loadB_oc = [&](int sl, int half, int ot) -> bf16x8 {
            int dy = sl / 3; int dxk = sl % 3; int s = dxk * 2 + half;
            int kb = (br * 72 + dy * 24 + s * 4 + q) * 32;
            return *(const bf16x8*)(owb + (size_t)(kb + ot * 16 + n) * 8);
        };
        auto offconv_pass = [&](int half, f32x4& cA, f32x4& cB) {
            bf16x8 a0 = loadA_oc(0), b0 = loadB_oc(0, half, 0), b1 = loadB_oc(0, half, 1);
#pragma unroll 1
            for (int sl = 0; sl < 9; ++sl) {
                bf16x8 na = a0, nb0 = b0, nb1 = b1;
                if (sl < 8) {
                    na = loadA_oc(sl + 1); nb0 = loadB_oc(sl + 1, half, 0); nb1 = loadB_oc(sl + 1, half, 1);
                }
                cA = __builtin_amdgcn_mfma_f32_16x16x32_bf16(a0, b0, cA, 0, 0, 0);
                cB = __builtin_amdgcn_mfma_f32_16x16x32_bf16(a0, b1, cB, 0, 0, 0);
                a0 = na; b0 = nb0; b1 = nb1;
            }
        };

        f32x4 c0 = (f32x4){0.f,0.f,0.f,0.f}, c1 = (f32x4){0.f,0.f,0.f,0.f};
        f32x4 c2 = (f32x4){0.f,0.f,0.f,0.f}, c3 = (f32x4){0.f,0.f,0.f,0.f};

        __syncthreads();           // window/sA/sWp free (prev sub done)
        stage_half(0);
        __syncthreads();
        offconv_pass(0, c0, c1);   // s even K-slices (ch 0..31)
        __syncthreads();           // all waves done reading half-0 window
        stage_half(1);
        __syncthreads();
        offconv_pass(1, c2, c3);   // s odd K-slices (ch 32..63)

        f32x4 acc2[2];
        acc2[0] = c0 + c2;
        acc2[1] = c1 + c3;

        // D-frags (+bias) -> sOff[j][px]; j=ot*16+n, px=w*16+q*4+r; j<27 only
#pragma unroll
        for (int ot = 0; ot < 2; ++ot) {
            int j = ot * 16 + n;
            if (j < 27) {
                float bias = obp[j];
#pragma unroll
                for (int r = 0; r < 4; ++r)
                    sOff[j * 66 + w * 16 + q * 4 + r] = acc2[ot][r] + bias;
            }
        }
        __syncthreads();   // sOff visible

        // ---- Phase A: bilinear coords + (mask*inbound)-folded weights ----
        for (int i2 = t; i2 < 576; i2 += 256) {
            int px = i2 & 63; int k = i2 >> 6;
            float dy = sOff[(2 * k) * 66 + px];
            float dx = sOff[(2 * k + 1) * 66 + px];
            float mm = sOff[(18 + k) * 66 + px];
            float m = sigf(mm);
            int ki = k / 3, kj = k % 3;
            float py  = (float)(row + ki - 1) + dy;
            float pxx = (float)(px + kj - 1) + dx;
            float y0f = floorf(py), x0f = floorf(pxx);
            float wy = py - y0f, wx = pxx - x0f;
            int y0 = (int)y0f, x0 = (int)x0f;
            float y0i = ((unsigned)y0 < 64u) ? 1.f : 0.f;
            float y1i = ((unsigned)(y0 + 1) < 64u) ? 1.f : 0.f;
            float x0i = ((unsigned)x0 < 64u) ? 1.f : 0.f;
            float x1i = ((unsigned)(x0 + 1) < 64u) ? 1.f : 0.f;
            float w00 = (1.f - wy) * (1.f - wx) * m * y0i * x0i;
            float w01 = (1.f - wy) * wx         * m * y0i * x1i;
            float w10 = wy         * (1.f - wx) * m * y1i * x0i;
            float w11 = wy         * wx         * m * y1i * x1i;
            int cy0 = min(max(y0, 0), 63),     cy1 = min(max(y0 + 1, 0), 63);
            int cx0 = min(max(x0, 0), 63),     cx1 = min(max(x0 + 1, 0), 63);
            // far: clamped corner row outside staged window [row-2, row+2]
            int s0 = cy0 - (row - 2); int s1 = cy1 - (row - 2);
            unsigned farb = (((unsigned)s0 > 4u) || ((unsigned)s1 > 4u)) ? 0x80000000u : 0u;
            sA[k * 64 + px] = make_uint2(((unsigned)(cy0 * 64 + cx0) | ((unsigned)(cy0 * 64 + cx1) << 16)) | farb,
                                         (unsigned)(cy1 * 64 + cx0) | ((unsigned)(cy1 * 64 + cx1) << 16));
            sWp[k * 64 + px] = (f16x4){(_Float16)w00, (_Float16)w01, (_Float16)w10, (_Float16)w11};
        }
        __syncthreads();

        // ---- per-half pipelined LDS gather + B-frag register pipeline ----
        auto loadB_mn = [&](int S, int ot) -> bf16x8 {
            int kb = (br * 72 + S * 4 + q) * 64;
            return *(const bf16x8*)(wBp + (size_t)(kb + ot * 16 + n) * 8);
        };

#define PROC(Ca, Cb, Cc, Cd, WV, Wa, Wb, Wc, Wd)                               \
        {                                                                      \
            float sacc[8];                                                     \
            sacc[0] = WV.x * blo(Ca.x); sacc[1] = WV.x * bhi(Ca.x);            \
            sacc[2] = WV.x * blo(Ca.y); sacc[3] = WV.x * bhi(Ca.y);            \
            sacc[4] = WV.x * blo(Ca.z); sacc[5] = WV.x * bhi(Ca.z);            \
            sacc[6] = WV.x * blo(Ca.w); sacc[7] = WV.x * bhi(Ca.w);            \
            sacc[0] += WV.y * blo(Cb.x); sacc[1] += WV.y * bhi(Cb.x);          \
            sacc[2] += WV.y * blo(Cb.y); sacc[3] += WV.y * bhi(Cb.y);          \
            sacc[4] += WV.y * blo(Cb.z); sacc[5] += WV.y * bhi(Cb.z);          \
            sacc[6] += WV.y * blo(Cb.w); sacc[7] += WV.y * bhi(Cb.w);          \
            sacc[0] += WV.z * blo(Cc.x); sacc[1] += WV.z * bhi(Cc.x);          \
            sacc[2] += WV.z * blo(Cc.y); sacc[3] += WV.z * bhi(Cc.y);          \
            sacc[4] += WV.z * blo(Cc.z); sacc[5] += WV.z * bhi(Cc.z);          \
            sacc[6] += WV.z * blo(Cc.w); sacc[7] += WV.z * bhi(Cc.w);          \
            sacc[0] += WV.w * blo(Cd.x); sacc[1] += WV.w * bhi(Cd.x);          \
            sacc[2] += WV.w * blo(Cd.y); sacc[3] += WV.w * bhi(Cd.y);          \
            sacc[4] += WV.w * blo(Cd.z); sacc[5] += WV.w * bhi(Cd.z);          \
            sacc[6] += WV.w * blo(Cd.w); sacc[7] += WV.w * bhi(Cd.w);          \
            bf16x8 af;                                                         \
            _Pragma("unroll")                                                  \
            for (int j = 0; j < 8; ++j) af[j] = (__bf16)sacc[j];               \
            acc[0] = __builtin_amdgcn_mfma_f32_16x16x32_bf16(af, Wa, acc[0], 0, 0, 0); \
            acc[1] = __builtin_amdgcn_mfma_f32_16x16x32_bf16(af, Wb, acc[1], 0, 0, 0); \
            acc[2] = __builtin_amdgcn_mfma_f32_16x16x32_bf16(af, Wc, acc[2], 0, 0, 0); \
            acc[3] = __builtin_amdgcn_mfma_f32_16x16x32_bf16(af, Wd, acc[3], 0, 0, 0); \
        }

        auto gather_pass = [&](int half) {
            const unsigned short* cbaseh = inT + q * 8 + half * 32;
            // prologue: tap 0 addresses, corner LDS loads, tap-0 B-frags
            uint2 aa = sA[pxl];
            f16x4 wv4 = sWp[pxl];
            float4 wv = make_float4((float)wv4[0], (float)wv4[1], (float)wv4[2], (float)wv4[3]);
            unsigned p00 = aa.x & 0xFFFu, p01 = (aa.x >> 16) & 0xFFFu;
            unsigned p10 = aa.y & 0xFFFu, p11 = aa.y >> 16;
            unsigned a00 = (unsigned)(((int)(p00 << 6)) + qb) ^ ((p00 & 7u) << 4);
            unsigned a01 = (unsigned)(((int)(p01 << 6)) + qb) ^ ((p01 & 7u) << 4);
            unsigned a10 = (unsigned)(((int)(p10 << 6)) + qb) ^ ((p10 & 7u) << 4);
            unsigned a11 = (unsigned)(((int)(p11 << 6)) + qb) ^ ((p11 & 7u) << 4);
            uint4 Ca = *(const uint4*)(arena + a00);
            uint4 Cb = *(const uint4*)(arena + a01);
            uint4 Cc = *(const uint4*)(arena + a10);
            uint4 Cd = *(const uint4*)(arena + a11);
            if (aa.x & 0x80000000u) {   // rare: window miss -> exact global path
                Ca = *(const uint4*)(cbaseh + (p00 << 6));
                Cb = *(const uint4*)(cbaseh + (p01 << 6));
                Cc = *(const uint4*)(cbaseh + (p10 << 6));
                Cd = *(const uint4*)(cbaseh + (p11 << 6));
            }
            bf16x8 Ba = loadB_mn(half, 0), Bb = loadB_mn(half, 1);
            bf16x8 Bc = loadB_mn(half, 2), Bd = loadB_mn(half, 3);
#pragma unroll 1
            for (int ktap = 0; ktap < 9; ++ktap) {
                uint4 Na = Ca, Nb = Cb, Nc = Cc, Nd = Cd;
                float4 wvn = wv;
                bf16x8 nBa = Ba, nBb = Bb, nBc = Bc, nBd = Bd;
                if (ktap < 8) {   // prefetch next tap: A corners (LDS) + B (global)
                    uint2 aan = sA[(ktap + 1) * 64 + pxl];
                    f16x4 wvn4 = sWp[(ktap + 1) * 64 + pxl];
                    wvn = make_float4((float)wvn4[0], (float)wvn4[1], (float)wvn4[2], (float)wvn4[3]);
                    unsigned q00 = aan.x & 0xFFFu, q01 = (aan.x >> 16) & 0xFFFu;
                    unsigned q10 = aan.y & 0xFFFu, q11 = aan.y >> 16;
                    unsigned b00 = (unsigned)(((int)(q00 << 6)) + qb) ^ ((q00 & 7u) << 4);
                    unsigned b01 = (unsigned)(((int)(q01 << 6)) + qb) ^ ((q01 & 7u) << 4);
                    unsigned b10 = (unsigned)(((int)(q10 << 6)) + qb) ^ ((q10 & 7u) << 4);
                    unsigned b11 = (unsigned)(((int)(q11 << 6)) + qb) ^ ((q11 & 7u) << 4);
                    Na = *(const uint4*)(arena + b00);
                    Nb = *(const uint4*)(arena + b01);
                    Nc = *(const uint4*)(arena + b10);
                    Nd = *(const uint4*)(arena + b11);
                    if (aan.x & 0x80000000u) {
                        Na = *(const uint4*)(cbaseh + (q00 << 6));
                        Nb = *(const uint4*)(cbaseh + (q01 << 6));
                        Nc = *(const uint4*)(cbaseh + (q10 << 6));
                        Nd = *(const uint4*)(cbaseh + (q11 << 6));
                    }
                    nBa = loadB_mn((ktap + 1) * 2 + half, 0);
                    nBb = loadB_mn((ktap + 1) * 2 + half, 1);
                    nBc = loadB_mn((ktap + 1) * 2 + half, 2);
                    nBd = loadB_mn((ktap + 1) * 2 + half, 3);
                }
                PROC(Ca, Cb, Cc, Cd, wv, Ba, Bb, Bc, Bd)
                Ca = Na; Cb = Nb; Cc = Nc; Cd = Nd;
                Ba = nBa; Bb = nBb; Bc = nBc; Bd = nBd;
                wv = wvn;
            }
        };

        gather_pass(1);            // window currently holds half-1
        __syncthreads();           // all waves done reading half-1 window
        stage_half(0);
        __syncthreads();
        gather_pass(0);
#undef PROC
    }

    // epilogue: direct D-scrambled coalesced store; K3 decodes.
    float* gp = p.ws + WS_GATES + ((size_t)((gate * 8 + b) * 64 + row) << 12);
#pragma unroll
    for (int ot = 0; ot < 4; ++ot)
        *(float4*)(gp + ((w * 4 + ot) * 64 + l) * 4) = *(float4*)&acc[ot];
}

// ---------------------------------------------------------------------------
// K3: pointwise ConvLSTM combine, reading D-scrambled gates (coalesced) and
//   decoding (o,px) for c/out access (16B-segment granularity).
//   grid: 8192 blocks of 256.
// ---------------------------------------------------------------------------
__global__ __launch_bounds__(256) void k3_lstm(Params p) {
    int T = blockIdx.x * 256 + threadIdx.x;        // [b][row][i] over scrambled
    int i = T & 4095; int row = (T >> 12) & 63; int b = T >> 18;
    const float* gp = p.ws + WS_GATES;
    size_t base = ((size_t)(b * 64 + row) << 12) + i;
    float gi = gp[base];
    float gf = gp[base + 1 * PLANE];
    float gc = gp[base + 2 * PLANE];
    float go = gp[base + 3 * PLANE];
    // decode scramble: i = ((w*4+ot)*64 + l)*4 + r
    int r = i & 3; int l = (i >> 2) & 63; int u = i >> 8;
    int w = u >> 2; int ot = u & 3;
    int o = ot * 16 + (l & 15);
    int px = w * 16 + (l >> 4) * 4 + r;
    size_t cidx = ((size_t)(b * 64 + o) << 12) + row * 64 + px;
    float cold = p.c[cidx];
    float ig = sigf(gi + cold * p.wci[o] + p.bi[o]);
    float fg = sigf(gf + cold * p.wcf[o] + p.bf[o]);
    float cn = fg * cold + ig * tanhfast(gc + p.bc[o]);
    float og = sigf(go + cn * p.wco[o] + p.bo[o]);
    p.out[cidx] = og * tanhfast(cn);
    p.out[cidx + PLANE] = cn;
}

// ---------------------------------------------------------------------------
extern "C" void kernel_launch(void* const* d_in, const int* in_sizes, int n_in,
                              void* d_out, int out_size, void* d_ws, size_t ws_size,
                              hipStream_t stream) {
    (void)in_sizes; (void)n_in; (void)out_size; (void)ws_size;
    Params P;
    P.x = (const float*)d_in[0];
    P.h = (const float*)d_in[1];
    P.c = (const float*)d_in[2];
    for (int i = 0; i < 8; ++i) {
        P.w[i]  = (const float*)d_in[3 + 3 * i];
        P.ow[i] = (const float*)d_in[4 + 3 * i];
        P.ob[i] = (const float*)d_in[5 + 3 * i];
    }
    P.bi  = (const float*)d_in[27];
    P.bf  = (const float*)d_in[28];
    P.bc  = (const float*)d_in[29];
    P.bo  = (const float*)d_in[30];
    P.wci = (const float*)d_in[31];
    P.wcf = (const float*)d_in[32];
    P.wco = (const float*)d_in[33];
    P.out = (float*)d_out;
    P.ws  = (float*)d_ws;

    k0_prep   <<<dim3(2753), dim3(256), 0, stream>>>(P);
    k2_fused  <<<dim3(2048), dim3(256), 0, stream>>>(P);
    k3_lstm   <<<dim3(8192), dim3(256), 0, stream>>>(P);
}